// Round 5
// baseline (129.796 us; speedup 1.0000x reference)
//
#include <hip/hip_runtime.h>
#include <math.h>

#define S 255
#define B 4

typedef _Float16 half8 __attribute__((ext_vector_type(8)));
typedef float f32x4 __attribute__((ext_vector_type(4)));

// ---- workspace layout (float offsets) ----
#define WS_APJ   0          // f16[4][65536]  A' frag, row j = A'[j-1], j=0 zeroed
#define WS_BPJ   131072     // f16[4][65536]  B' frag, j-shifted
#define WS_VTF   262144     // f16[4][65536]  V^T frag: (col d, k=j)
#define WS_AP    393216     // f32[1020][256] row-major A'
#define WS_MFG   654336     // f16[4096] M in B-frag order
#define WS_CONST 656384     // f32[8]
#define WS_QLOG  656392     // f32[4][8][256]
#define WS_KLOG  664584     // f32[4][8][256]  (ends 672776)

#define PLS 264

__device__ __forceinline__ half8 cvt8(float4 a, float4 b) {
    half8 h;
    h[0]=(_Float16)a.x; h[1]=(_Float16)a.y; h[2]=(_Float16)a.z; h[3]=(_Float16)a.w;
    h[4]=(_Float16)b.x; h[5]=(_Float16)b.y; h[6]=(_Float16)b.z; h[7]=(_Float16)b.w;
    return h;
}

// ===========================================================================
// K1: 0..63 V->VTF | 64..127 A' | 128..191 B' | 192..207 qklog | 208 misc
// (verified body)
// ===========================================================================
__global__ __launch_bounds__(256) void k1(
    const float* __restrict__ desc, const float* __restrict__ nve,
    const float* __restrict__ qW, const float* __restrict__ qb,
    const float* __restrict__ kW, const float* __restrict__ kb,
    const float* __restrict__ vW, const float* __restrict__ vb,
    const float* __restrict__ eW1, const float* __restrict__ eb1,
    const float* __restrict__ eW2, const float* __restrict__ eb2,
    const float* __restrict__ aW, float* __restrict__ ws)
{
    const int blk = blockIdx.x;
    const int tid = threadIdx.x;
    __shared__ _Float16 Af[4096];
    __shared__ _Float16 Bf[4096];
    const int wave = tid >> 6, lane = tid & 63;
    const int m16 = lane & 15, quad = lane >> 4;
    const int sr = tid & 63, sko = (tid >> 6) * 16;
    const half8 z8 = {(_Float16)0,(_Float16)0,(_Float16)0,(_Float16)0,
                      (_Float16)0,(_Float16)0,(_Float16)0,(_Float16)0};

    if (blk < 192) {
        const float *X, *W; int M, wst, wof, jobt, sub = blk;
        if (sub < 64)       { X=nve;  W=vW;  M=1024; wst=256; wof=0;   jobt=0; }
        else if (sub < 128) { X=desc; W=eW1; M=1020; wst=512; wof=0;   jobt=1; sub-=64; }
        else                { X=desc; W=eW1; M=1020; wst=512; wof=256; jobt=2; sub-=128; }
        int mBase = (sub>>2)*64, nBase = (sub&3)*64;
        f32x4 acc[2][2] = {};
        for (int k0 = 0; k0 < 256; k0 += 64) {
            half8 xa[2], wb[2];
            int xr = mBase + sr, wr = nBase + sr;
            #pragma unroll
            for (int hh = 0; hh < 2; hh++) {
                int kk = k0 + sko + hh*8;
                if (xr < M) xa[hh] = cvt8(*(const float4*)&X[xr*256 + kk],
                                          *(const float4*)&X[xr*256 + kk + 4]);
                else xa[hh] = z8;
                wb[hh] = cvt8(*(const float4*)&W[wr*wst + wof + kk],
                              *(const float4*)&W[wr*wst + wof + kk + 4]);
            }
            __syncthreads();
            #pragma unroll
            for (int hh = 0; hh < 2; hh++) {
                int krel = sko + hh*8;
                int c = krel >> 5, q2 = (krel >> 3) & 3;
                int ld = (sr & 15) + 16*q2, rt = sr >> 4;
                *(half8*)&Af[((rt*2 + c)*64 + ld)*8] = xa[hh];
                *(half8*)&Bf[((rt*2 + c)*64 + ld)*8] = wb[hh];
            }
            __syncthreads();
            int rt0 = (wave >> 1)*2, ct0 = (wave & 1)*2;
            #pragma unroll
            for (int c = 0; c < 2; c++) {
                half8 A0 = *(const half8*)&Af[(((rt0    )*2 + c)*64 + lane)*8];
                half8 A1 = *(const half8*)&Af[(((rt0 + 1)*2 + c)*64 + lane)*8];
                half8 B0 = *(const half8*)&Bf[(((ct0    )*2 + c)*64 + lane)*8];
                half8 B1 = *(const half8*)&Bf[(((ct0 + 1)*2 + c)*64 + lane)*8];
                acc[0][0] = __builtin_amdgcn_mfma_f32_16x16x32_f16(A0, B0, acc[0][0], 0,0,0);
                acc[0][1] = __builtin_amdgcn_mfma_f32_16x16x32_f16(A0, B1, acc[0][1], 0,0,0);
                acc[1][0] = __builtin_amdgcn_mfma_f32_16x16x32_f16(A1, B0, acc[1][0], 0,0,0);
                acc[1][1] = __builtin_amdgcn_mfma_f32_16x16x32_f16(A1, B1, acc[1][1], 0,0,0);
            }
        }
        int rt0 = (wave >> 1)*2, ct0 = (wave & 1)*2;
        if (jobt == 0) {
            _Float16* vtf = (_Float16*)(ws + WS_VTF);
            #pragma unroll
            for (int ci = 0; ci < 2; ci++) {
                int col = nBase + (ct0 + ci)*16 + m16;
                float bv = vb[col];
                int ct = col >> 4, n = col & 15;
                #pragma unroll
                for (int ri = 0; ri < 2; ri++)
                    #pragma unroll
                    for (int r = 0; r < 4; r++) {
                        int rr = mBase + (rt0 + ri)*16 + quad*4 + r;
                        int bb = rr >> 8, j = rr & 255;
                        int js = j >> 5, qv = (j >> 3) & 3, ev = j & 7;
                        float o = acc[ri][ci][r] + bv;
                        vtf[bb*65536 + (((ct*8 + js)*64 + n + 16*qv) << 3) + ev] = (_Float16)o;
                    }
            }
        } else {
            _Float16* OJ = (_Float16*)(ws + ((jobt == 1) ? WS_APJ : WS_BPJ));
            #pragma unroll
            for (int ci = 0; ci < 2; ci++) {
                int col = nBase + (ct0 + ci)*16 + m16;
                float bv = (jobt == 1) ? eb1[col] : 0.f;
                int ks = col >> 5, q = (col >> 3) & 3, e = col & 7;
                #pragma unroll
                for (int ri = 0; ri < 2; ri++)
                    #pragma unroll
                    for (int r = 0; r < 4; r++) {
                        int rr = mBase + (rt0 + ri)*16 + quad*4 + r;
                        if (rr < 1020) {
                            float o = acc[ri][ci][r] + bv;
                            int bb = rr / 255;
                            int j = rr - bb*255 + 1;
                            int jt = j >> 4, mm = j & 15;
                            OJ[bb*65536 + (((jt*8 + ks)*64 + mm + 16*q) << 3) + e] = (_Float16)o;
                            if (jobt == 1) ws[WS_AP + rr*256 + col] = o;
                        }
                    }
            }
        }
    } else if (blk < 208) {
        // qklog = nve @ fold (fold in Bf)
        {
            int d = tid;
            float f[16] = {0,0,0,0,0,0,0,0,0,0,0,0,0,0,0,0};
            for (int hd = 0; hd < 32; hd++) {
                float wq = aW[hd], wk = aW[32+hd];
                #pragma unroll
                for (int h = 0; h < 8; h++) {
                    f[h]   = fmaf(wq, qW[(h*32+hd)*256 + d], f[h]);
                    f[8+h] = fmaf(wk, kW[(h*32+hd)*256 + d], f[8+h]);
                }
            }
            int ksd = d >> 5, q2 = (d >> 3) & 3, jj = d & 7;
            #pragma unroll
            for (int n = 0; n < 16; n++)
                Bf[((ksd*64 + n + 16*q2))*8 + jj] = (_Float16)f[n];
        }
        __syncthreads();
        int mBase = (blk - 192)*64;
        f32x4 acc = {0.f,0.f,0.f,0.f};
        for (int k0 = 0; k0 < 256; k0 += 64) {
            half8 xa[2];
            #pragma unroll
            for (int hh = 0; hh < 2; hh++) {
                int kk = k0 + sko + hh*8;
                xa[hh] = cvt8(*(const float4*)&nve[(mBase + sr)*256 + kk],
                              *(const float4*)&nve[(mBase + sr)*256 + kk + 4]);
            }
            __syncthreads();
            #pragma unroll
            for (int hh = 0; hh < 2; hh++) {
                int krel = sko + hh*8;
                int c = krel >> 5, q2 = (krel >> 3) & 3;
                int ld = (sr & 15) + 16*q2, rt = sr >> 4;
                *(half8*)&Af[((rt*2 + c)*64 + ld)*8] = xa[hh];
            }
            __syncthreads();
            #pragma unroll
            for (int c = 0; c < 2; c++) {
                half8 A  = *(const half8*)&Af[((wave*2 + c)*64 + lane)*8];
                half8 Bv = *(const half8*)&Bf[(((k0 >> 5) + c)*64 + lane)*8];
                acc = __builtin_amdgcn_mfma_f32_16x16x32_f16(A, Bv, acc, 0,0,0);
            }
        }
        #pragma unroll
        for (int r = 0; r < 4; r++) {
            int rr = mBase + wave*16 + quad*4 + r;
            int bb = rr >> 8, tt2 = rr & 255;
            if (m16 < 8) ws[WS_QLOG + (bb*8 + m16)*256 + tt2] = acc[r];
            else         ws[WS_KLOG + (bb*8 + m16 - 8)*256 + tt2] = acc[r];
        }
    } else {
        // misc: MFG + CONST + zero j=0 frag rows
        _Float16* mfg = (_Float16*)(ws + WS_MFG);
        int k = tid;
        float a8[8] = {0,0,0,0,0,0,0,0};
        for (int hd = 0; hd < 32; hd++) {
            float we = aW[64+hd];
            #pragma unroll
            for (int h = 0; h < 8; h++)
                a8[h] = fmaf(we, eW2[(h*32+hd)*256 + k], a8[h]);
        }
        int ksd = k >> 5, q2 = (k >> 3) & 3, jj = k & 7;
        #pragma unroll
        for (int h = 0; h < 8; h++)
            mfg[((ksd*64 + h + 16*q2))*8 + jj] = (_Float16)a8[h];
        #pragma unroll
        for (int n = 8; n < 16; n++)
            mfg[((ksd*64 + n + 16*q2))*8 + jj] = (_Float16)0.f;
        {
            _Float16* apj = (_Float16*)(ws + WS_APJ);
            _Float16* bpj = (_Float16*)(ws + WS_BPJ);
            int ks0 = tid >> 5, qz = (tid >> 3) & 3, ez = tid & 7;
            int ad = ((ks0*64 + 16*qz) << 3) + ez;
            #pragma unroll
            for (int bb = 0; bb < 4; bb++) {
                apj[bb*65536 + ad] = (_Float16)0.f;
                bpj[bb*65536 + ad] = (_Float16)0.f;
            }
        }
        {   // CONST parallel
            int h = tid >> 5, hd = tid & 31;
            float c = aW[64+hd]*eb2[h*32+hd] + aW[hd]*qb[h*32+hd] + aW[32+hd]*kb[h*32+hd];
            #pragma unroll
            for (int off = 16; off >= 1; off >>= 1)
                c += __shfl_xor(c, off, 32);
            if (hd == 0) ws[WS_CONST + h] = c;
        }
    }
}

// ===========================================================================
// K3: 4 i-values per block. grid (64,4) x 1024 threads (16 waves).
// Every bpj/vtf/mfg fragment load serves 4 outputs. Wave w owns j-tile w.
// ===========================================================================
__global__ __launch_bounds__(1024, 4) void k3(
    const float* __restrict__ ln_g, const float* __restrict__ ln_b,
    const float* __restrict__ ab, const float* __restrict__ ws,
    float* __restrict__ out)
{
    const int b = blockIdx.y, gx = blockIdx.x;
    const int i_base = gx*4;
    const int tid = threadIdx.x;
    const int wave = tid >> 6, lane = tid & 63;
    const int m16 = lane & 15, quad = lane >> 4;
    const bool sp = (gx == 0);   // i_base == 0 special

    __shared__ float klds[2048];
    __shared__ float PL[4][8*PLS];
    __shared__ float gL[256], bL[256];
    __shared__ float aLs[4][256];
    __shared__ float2 st[4][256];
    __shared__ float stG[4][256];
    __shared__ float stSB[256], stQB[256], stSA[256], stQA[256];
    __shared__ float baseh[32], sms[32], saqa[32];

    const half8 z8 = {(_Float16)0,(_Float16)0,(_Float16)0,(_Float16)0,
                      (_Float16)0,(_Float16)0,(_Float16)0,(_Float16)0};
    half8 ones8;
    #pragma unroll
    for (int e = 0; e < 8; e++) ones8[e] = (_Float16)1.0f;

    // ---- loads ----
    #pragma unroll
    for (int t = 0; t < 2; t++)
        klds[tid + t*1024] = ws[WS_KLOG + b*2048 + tid + t*1024];
    if (tid < 256) { gL[tid] = ln_g[tid]; }
    else if (tid < 512) { bL[tid-256] = ln_b[tid-256]; }
    {
        int hf = tid >> 8, t8 = tid & 255;
        int ih = i_base + hf;
        float av = (ih >= 1) ? ws[WS_AP + ((size_t)(b*S + ih - 1))*256 + t8] : 0.f;
        aLs[hf][t8] = av;
        float s1 = av, s2 = av*av;
        #pragma unroll
        for (int off = 32; off >= 1; off >>= 1) {
            s1 += __shfl_xor(s1, off, 64);
            s2 += __shfl_xor(s2, off, 64);
        }
        int hw = wave >> 2, sub = wave & 3;
        if (lane == 0) { saqa[hw*8 + sub] = s1; saqa[hw*8 + 4 + sub] = s2; }
    }
    if (tid < 32) {
        int h = tid & 7, ihf = tid >> 3;
        baseh[tid] = ws[WS_QLOG + (b*8+h)*256 + (i_base + ihf)] + ab[0] + ws[WS_CONST + h];
    }
    __syncthreads();

    const _Float16* mfg = (const _Float16*)(ws + WS_MFG);
    const _Float16* bpj = (const _Float16*)(ws + WS_BPJ) + b*65536;
    const _Float16* apj = (const _Float16*)(ws + WS_APJ) + b*65536;
    const _Float16* vtf = (const _Float16*)(ws + WS_VTF) + b*65536;

    // ---- per-j stats via MFMA: wave owns j-tile = wave ----
    if (!sp) {
        f32x4 accGS = {}, accQB = {};
        #pragma unroll
        for (int ks = 0; ks < 8; ks++) {
            half8 bb = *(const half8*)&bpj[((wave*8+ks)*64 + lane) << 3];
            half8 ags;
            if (m16 < 4)
                ags = cvt8(*(const float4*)&aLs[m16][ks*32 + quad*8],
                           *(const float4*)&aLs[m16][ks*32 + quad*8 + 4]);
            else if (m16 == 4) ags = ones8;
            else ags = z8;
            accGS = __builtin_amdgcn_mfma_f32_16x16x32_f16(ags, bb, accGS, 0,0,0);
            accQB = __builtin_amdgcn_mfma_f32_16x16x32_f16(bb,  bb, accQB, 0,0,0);
        }
        int j = wave*16 + m16;
        if (quad == 0) {
            stG[0][j] = accGS[0]; stG[1][j] = accGS[1];
            stG[2][j] = accGS[2]; stG[3][j] = accGS[3];
        }
        if (quad == 1) stSB[j] = accGS[0];          // row 4
        if (quad == (m16 >> 2)) stQB[j] = accQB[m16 & 3];
    } else {
        f32x4 accX = {}, accSA = {}, accG0 = {}, accQA = {}, accQB = {};
        #pragma unroll
        for (int ks = 0; ks < 8; ks++) {
            int idx = ((wave*8+ks)*64 + lane) << 3;
            half8 bb = *(const half8*)&bpj[idx];
            half8 aa = *(const half8*)&apj[idx];
            half8 a1 = (m16 == 0) ? ones8 : z8;
            half8 agsX;
            if (m16 < 3)
                agsX = cvt8(*(const float4*)&aLs[m16+1][ks*32 + quad*8],
                            *(const float4*)&aLs[m16+1][ks*32 + quad*8 + 4]);
            else if (m16 == 3) agsX = ones8;
            else agsX = z8;
            accX  = __builtin_amdgcn_mfma_f32_16x16x32_f16(agsX, bb, accX,  0,0,0);
            accSA = __builtin_amdgcn_mfma_f32_16x16x32_f16(a1,   aa, accSA, 0,0,0);
            accG0 = __builtin_amdgcn_mfma_f32_16x16x32_f16(aa,   bb, accG0, 0,0,0);
            accQA = __builtin_amdgcn_mfma_f32_16x16x32_f16(aa,   aa, accQA, 0,0,0);
            accQB = __builtin_amdgcn_mfma_f32_16x16x32_f16(bb,   bb, accQB, 0,0,0);
        }
        int j = wave*16 + m16;
        if (quad == 0) {
            stG[1][j] = accX[0]; stG[2][j] = accX[1]; stG[3][j] = accX[2];
            stSB[j] = accX[3];                      // row 3
            stSA[j] = accSA[0];                     // row 0
        }
        if (quad == (m16 >> 2)) {
            int r = m16 & 3;
            stG[0][j] = accG0[r]; stQA[j] = accQA[r]; stQB[j] = accQB[r];
        }
    }
    __syncthreads();

    {   // per-(i,j) (inv, -mu*inv): thread = hf*256 + j
        int hf = tid >> 8, j = tid & 255;
        float2 v; v.x = 0.f; v.y = 0.f;
        if (j >= 1) {
            float sa, qa;
            if (sp && hf == 0) { sa = stSA[j]; qa = stQA[j]; }
            else {
                int base = hf*8;
                sa = saqa[base+0] + saqa[base+1] + saqa[base+2] + saqa[base+3];
                qa = saqa[base+4] + saqa[base+5] + saqa[base+6] + saqa[base+7];
            }
            float g = stG[hf][j];
            float sb = stSB[j], qb2 = stQB[j];
            float mu  = (sa + sb) * (1.0f/256.0f);
            float var = (qa + qb2 + 2.f*g) * (1.0f/256.0f) - mu*mu;
            float inv = rsqrtf(var + 1e-5f);
            v.x = inv; v.y = -mu*inv;
        }
        st[hf][j] = v;
    }
    __syncthreads();

    // ---- logits MFMA: wave owns j-tile = wave; 4 i's per bp load ----
    f32x4 acc[4] = {};
    float2 sv[4];
    #pragma unroll
    for (int ii = 0; ii < 4; ii++)
        sv[ii] = st[ii][wave*16 + m16];

    #pragma unroll
    for (int ks = 0; ks < 8; ks++) {
        int k = ks*32 + quad*8;
        float4 g0 = *(const float4*)&gL[k], g1 = *(const float4*)&gL[k+4];
        float4 b0 = *(const float4*)&bL[k], b1 = *(const float4*)&bL[k+4];
        half8 bf = *(const half8*)&mfg[(ks*64 + lane) << 3];
        int idx2 = ((wave*8 + ks)*64 + lane) << 3;
        half8 bp = *(const half8*)&bpj[idx2];
        half8 app = sp ? *(const half8*)&apj[idx2] : z8;
        float ga[8] = {g0.x,g0.y,g0.z,g0.w,g1.x,g1.y,g1.z,g1.w};
        float be[8] = {b0.x,b0.y,b0.z,b0.w,b1.x,b1.y,b1.z,b1.w};
        #pragma unroll
        for (int ii = 0; ii < 4; ii++) {
            float4 x0 = *(const float4*)&aLs[ii][k];
            float4 x1 = *(const float4*)&aLs[ii][k+4];
            float aa[8] = {x0.x,x0.y,x0.z,x0.w,x1.x,x1.y,x1.z,x1.w};
            half8 af;
            #pragma unroll
            for (int e = 0; e < 8; e++) {
                float bpe = (float)bp[e];
                float c = ((sp && ii == 0) ? (float)app[e] : aa[e]) + bpe;
                float w = fmaf(fmaf(c, sv[ii].x, sv[ii].y), ga[e], be[e]);
                af[e] = (_Float16)fmaxf(w, 0.f);
            }
            acc[ii] = __builtin_amdgcn_mfma_f32_16x16x32_f16(af, bf, acc[ii], 0,0,0);
        }
    }

    if (m16 < 8) {
        #pragma unroll
        for (int ii = 0; ii < 4; ii++) {
            float basev = baseh[ii*8 + m16];
            #pragma unroll
            for (int r = 0; r < 4; r++) {
                int jr = wave*16 + quad*4 + r;
                float val = basev + klds[m16*256 + jr];
                val += (jr == 0) ? -1e9f : acc[ii][r];
                PL[ii][m16*PLS + jr] = val;
            }
        }
    }
    __syncthreads();

    // ---- softmax: wave w owns rows 2w, 2w+1 of 32 (row = ii*8 + h) ----
    float* attnOut = out + 262144;
    #pragma unroll
    for (int hh = 0; hh < 2; hh++) {
        int row = wave*2 + hh;
        int ihf = row >> 3, h = row & 7;
        float* PLp = PL[ihf];
        int iv = i_base + ihf;
        float4 v = *(const float4*)&PLp[h*PLS + lane*4];
        float mv = fmaxf(fmaxf(v.x, v.y), fmaxf(v.z, v.w));
        #pragma unroll
        for (int off = 32; off >= 1; off >>= 1)
            mv = fmaxf(mv, __shfl_xor(mv, off, 64));
        float4 p;
        p.x = __expf(v.x - mv); p.y = __expf(v.y - mv);
        p.z = __expf(v.z - mv); p.w = __expf(v.w - mv);
        float ss = p.x + p.y + p.z + p.w;
        #pragma unroll
        for (int off = 32; off >= 1; off >>= 1)
            ss += __shfl_xor(ss, off, 64);
        *(float4*)&PLp[h*PLS + lane*4] = p;
        if (lane == 0) sms[row] = ss;
        float rs = 1.0f / ss;
        float4 ao;
        ao.x = p.x*rs; ao.y = p.y*rs; ao.z = p.z*rs; ao.w = p.w*rs;
        *(float4*)&attnOut[((b*8+h)*256 + iv)*256 + lane*4] = ao;
    }
    __syncthreads();

    // ---- ctx via MFMA: wave owns col-tile ct = wave; 4 i's per vtf load ----
    {
        f32x4 cacc[4] = {};
        int ct = wave;
        #pragma unroll
        for (int js = 0; js < 8; js++) {
            half8 bf = *(const half8*)&vtf[((ct*8 + js)*64 + lane) << 3];
            #pragma unroll
            for (int ii = 0; ii < 4; ii++) {
                half8 af;
                if (m16 < 8) {
                    float4 p0 = *(const float4*)&PL[ii][m16*PLS + js*32 + quad*8];
                    float4 p1 = *(const float4*)&PL[ii][m16*PLS + js*32 + quad*8 + 4];
                    af = cvt8(p0, p1);
                } else af = z8;
                cacc[ii] = __builtin_amdgcn_mfma_f32_16x16x32_f16(af, bf, cacc[ii], 0,0,0);
            }
        }
        int h = ct >> 1;
        if (quad == (h >> 2)) {
            #pragma unroll
            for (int ii = 0; ii < 4; ii++) {
                out[(b*256 + i_base + ii)*256 + ct*16 + m16]
                    = cacc[ii][h & 3] * (1.0f / sms[ii*8 + h]);
            }
        }
    }
}

// ---------------------------------------------------------------------------
extern "C" void kernel_launch(void* const* d_in, const int* in_sizes, int n_in,
                              void* d_out, int out_size, void* d_ws, size_t ws_size,
                              hipStream_t stream)
{
    const float* desc = (const float*)d_in[0];
    const float* nve  = (const float*)d_in[1];
    const float* qW   = (const float*)d_in[2];
    const float* qb   = (const float*)d_in[3];
    const float* kW   = (const float*)d_in[4];
    const float* kb   = (const float*)d_in[5];
    const float* vW   = (const float*)d_in[6];
    const float* vb   = (const float*)d_in[7];
    const float* eW1  = (const float*)d_in[8];
    const float* eb1  = (const float*)d_in[9];
    const float* ln_g = (const float*)d_in[10];
    const float* ln_b = (const float*)d_in[11];
    const float* eW2  = (const float*)d_in[12];
    const float* eb2  = (const float*)d_in[13];
    const float* aW   = (const float*)d_in[14];
    const float* ab   = (const float*)d_in[15];
    float* ws  = (float*)d_ws;
    float* out = (float*)d_out;

    k1<<<dim3(209), 256, 0, stream>>>(desc, nve, qW, qb, kW, kb, vW, vb,
                                      eW1, eb1, eW2, eb2, aW, ws);
    k3<<<dim3(64, 4), 1024, 0, stream>>>(ln_g, ln_b, ab, ws, out);
}

// Round 7
// 117.786 us; speedup vs baseline: 1.1020x; 1.1020x over previous
//
#include <hip/hip_runtime.h>
#include <math.h>

#define S 255
#define B 4

typedef _Float16 half8 __attribute__((ext_vector_type(8)));
typedef _Float16 half4 __attribute__((ext_vector_type(4)));
typedef float f32x4 __attribute__((ext_vector_type(4)));

// ---- workspace layout (float offsets) ----
#define WS_APJ   0          // f16[4][65536]  A' frag, row j = A'[j-1], j=0 zeroed
#define WS_BPJ   131072     // f16[4][65536]  B' frag, j-shifted
#define WS_VTF   262144     // f16[4][65536]  V^T frag: (col d, k=j)
#define WS_AP    393216     // f32[1020][256] row-major A'
#define WS_MFG   654336     // f16[4096] M in B-frag order
#define WS_CONST 656384     // f32[8]
#define WS_QLOG  656392     // f32[4][8][256]
#define WS_KLOG  664584     // f32[4][8][256]  (ends 672776)

#define PLS 272

__device__ __forceinline__ half8 cvt8(float4 a, float4 b) {
    half8 h;
    h[0]=(_Float16)a.x; h[1]=(_Float16)a.y; h[2]=(_Float16)a.z; h[3]=(_Float16)a.w;
    h[4]=(_Float16)b.x; h[5]=(_Float16)b.y; h[6]=(_Float16)b.z; h[7]=(_Float16)b.w;
    return h;
}

__device__ __forceinline__ half8 splat8(float x) {
    _Float16 hv = (_Float16)x;
    half8 v;
    #pragma unroll
    for (int e = 0; e < 8; e++) v[e] = hv;
    return v;
}

// ===========================================================================
// K1: 0..63 V->VTF | 64..127 A' | 128..191 B' | 192..207 qklog | 208 misc
// (verified body)
// ===========================================================================
__global__ __launch_bounds__(256) void k1(
    const float* __restrict__ desc, const float* __restrict__ nve,
    const float* __restrict__ qW, const float* __restrict__ qb,
    const float* __restrict__ kW, const float* __restrict__ kb,
    const float* __restrict__ vW, const float* __restrict__ vb,
    const float* __restrict__ eW1, const float* __restrict__ eb1,
    const float* __restrict__ eW2, const float* __restrict__ eb2,
    const float* __restrict__ aW, float* __restrict__ ws)
{
    const int blk = blockIdx.x;
    const int tid = threadIdx.x;
    __shared__ _Float16 Af[4096];
    __shared__ _Float16 Bf[4096];
    const int wave = tid >> 6, lane = tid & 63;
    const int m16 = lane & 15, quad = lane >> 4;
    const int sr = tid & 63, sko = (tid >> 6) * 16;
    const half8 z8 = {(_Float16)0,(_Float16)0,(_Float16)0,(_Float16)0,
                      (_Float16)0,(_Float16)0,(_Float16)0,(_Float16)0};

    if (blk < 192) {
        const float *X, *W; int M, wst, wof, jobt, sub = blk;
        if (sub < 64)       { X=nve;  W=vW;  M=1024; wst=256; wof=0;   jobt=0; }
        else if (sub < 128) { X=desc; W=eW1; M=1020; wst=512; wof=0;   jobt=1; sub-=64; }
        else                { X=desc; W=eW1; M=1020; wst=512; wof=256; jobt=2; sub-=128; }
        int mBase = (sub>>2)*64, nBase = (sub&3)*64;
        f32x4 acc[2][2] = {};
        for (int k0 = 0; k0 < 256; k0 += 64) {
            half8 xa[2], wb[2];
            int xr = mBase + sr, wr = nBase + sr;
            #pragma unroll
            for (int hh = 0; hh < 2; hh++) {
                int kk = k0 + sko + hh*8;
                if (xr < M) xa[hh] = cvt8(*(const float4*)&X[xr*256 + kk],
                                          *(const float4*)&X[xr*256 + kk + 4]);
                else xa[hh] = z8;
                wb[hh] = cvt8(*(const float4*)&W[wr*wst + wof + kk],
                              *(const float4*)&W[wr*wst + wof + kk + 4]);
            }
            __syncthreads();
            #pragma unroll
            for (int hh = 0; hh < 2; hh++) {
                int krel = sko + hh*8;
                int c = krel >> 5, q2 = (krel >> 3) & 3;
                int ld = (sr & 15) + 16*q2, rt = sr >> 4;
                *(half8*)&Af[((rt*2 + c)*64 + ld)*8] = xa[hh];
                *(half8*)&Bf[((rt*2 + c)*64 + ld)*8] = wb[hh];
            }
            __syncthreads();
            int rt0 = (wave >> 1)*2, ct0 = (wave & 1)*2;
            #pragma unroll
            for (int c = 0; c < 2; c++) {
                half8 A0 = *(const half8*)&Af[(((rt0    )*2 + c)*64 + lane)*8];
                half8 A1 = *(const half8*)&Af[(((rt0 + 1)*2 + c)*64 + lane)*8];
                half8 B0 = *(const half8*)&Bf[(((ct0    )*2 + c)*64 + lane)*8];
                half8 B1 = *(const half8*)&Bf[(((ct0 + 1)*2 + c)*64 + lane)*8];
                acc[0][0] = __builtin_amdgcn_mfma_f32_16x16x32_f16(A0, B0, acc[0][0], 0,0,0);
                acc[0][1] = __builtin_amdgcn_mfma_f32_16x16x32_f16(A0, B1, acc[0][1], 0,0,0);
                acc[1][0] = __builtin_amdgcn_mfma_f32_16x16x32_f16(A1, B0, acc[1][0], 0,0,0);
                acc[1][1] = __builtin_amdgcn_mfma_f32_16x16x32_f16(A1, B1, acc[1][1], 0,0,0);
            }
        }
        int rt0 = (wave >> 1)*2, ct0 = (wave & 1)*2;
        if (jobt == 0) {
            _Float16* vtf = (_Float16*)(ws + WS_VTF);
            #pragma unroll
            for (int ci = 0; ci < 2; ci++) {
                int col = nBase + (ct0 + ci)*16 + m16;
                float bv = vb[col];
                int ct = col >> 4, n = col & 15;
                #pragma unroll
                for (int ri = 0; ri < 2; ri++)
                    #pragma unroll
                    for (int r = 0; r < 4; r++) {
                        int rr = mBase + (rt0 + ri)*16 + quad*4 + r;
                        int bb = rr >> 8, j = rr & 255;
                        int js = j >> 5, qv = (j >> 3) & 3, ev = j & 7;
                        float o = acc[ri][ci][r] + bv;
                        vtf[bb*65536 + (((ct*8 + js)*64 + n + 16*qv) << 3) + ev] = (_Float16)o;
                    }
            }
        } else {
            _Float16* OJ = (_Float16*)(ws + ((jobt == 1) ? WS_APJ : WS_BPJ));
            #pragma unroll
            for (int ci = 0; ci < 2; ci++) {
                int col = nBase + (ct0 + ci)*16 + m16;
                float bv = (jobt == 1) ? eb1[col] : 0.f;
                int ks = col >> 5, q = (col >> 3) & 3, e = col & 7;
                #pragma unroll
                for (int ri = 0; ri < 2; ri++)
                    #pragma unroll
                    for (int r = 0; r < 4; r++) {
                        int rr = mBase + (rt0 + ri)*16 + quad*4 + r;
                        if (rr < 1020) {
                            float o = acc[ri][ci][r] + bv;
                            int bb = rr / 255;
                            int j = rr - bb*255 + 1;
                            int jt = j >> 4, mm = j & 15;
                            OJ[bb*65536 + (((jt*8 + ks)*64 + mm + 16*q) << 3) + e] = (_Float16)o;
                            if (jobt == 1) ws[WS_AP + rr*256 + col] = o;
                        }
                    }
            }
        }
    } else if (blk < 208) {
        // qklog = nve @ fold (fold in Bf)
        {
            int d = tid;
            float f[16] = {0,0,0,0,0,0,0,0,0,0,0,0,0,0,0,0};
            for (int hd = 0; hd < 32; hd++) {
                float wq = aW[hd], wk = aW[32+hd];
                #pragma unroll
                for (int h = 0; h < 8; h++) {
                    f[h]   = fmaf(wq, qW[(h*32+hd)*256 + d], f[h]);
                    f[8+h] = fmaf(wk, kW[(h*32+hd)*256 + d], f[8+h]);
                }
            }
            int ksd = d >> 5, q2 = (d >> 3) & 3, jj = d & 7;
            #pragma unroll
            for (int n = 0; n < 16; n++)
                Bf[((ksd*64 + n + 16*q2))*8 + jj] = (_Float16)f[n];
        }
        __syncthreads();
        int mBase = (blk - 192)*64;
        f32x4 acc = {0.f,0.f,0.f,0.f};
        for (int k0 = 0; k0 < 256; k0 += 64) {
            half8 xa[2];
            #pragma unroll
            for (int hh = 0; hh < 2; hh++) {
                int kk = k0 + sko + hh*8;
                xa[hh] = cvt8(*(const float4*)&nve[(mBase + sr)*256 + kk],
                              *(const float4*)&nve[(mBase + sr)*256 + kk + 4]);
            }
            __syncthreads();
            #pragma unroll
            for (int hh = 0; hh < 2; hh++) {
                int krel = sko + hh*8;
                int c = krel >> 5, q2 = (krel >> 3) & 3;
                int ld = (sr & 15) + 16*q2, rt = sr >> 4;
                *(half8*)&Af[((rt*2 + c)*64 + ld)*8] = xa[hh];
            }
            __syncthreads();
            #pragma unroll
            for (int c = 0; c < 2; c++) {
                half8 A  = *(const half8*)&Af[((wave*2 + c)*64 + lane)*8];
                half8 Bv = *(const half8*)&Bf[(((k0 >> 5) + c)*64 + lane)*8];
                acc = __builtin_amdgcn_mfma_f32_16x16x32_f16(A, Bv, acc, 0,0,0);
            }
        }
        #pragma unroll
        for (int r = 0; r < 4; r++) {
            int rr = mBase + wave*16 + quad*4 + r;
            int bb = rr >> 8, tt2 = rr & 255;
            if (m16 < 8) ws[WS_QLOG + (bb*8 + m16)*256 + tt2] = acc[r];
            else         ws[WS_KLOG + (bb*8 + m16 - 8)*256 + tt2] = acc[r];
        }
    } else {
        // misc: MFG + CONST + zero j=0 frag rows
        _Float16* mfg = (_Float16*)(ws + WS_MFG);
        int k = tid;
        float a8[8] = {0,0,0,0,0,0,0,0};
        for (int hd = 0; hd < 32; hd++) {
            float we = aW[64+hd];
            #pragma unroll
            for (int h = 0; h < 8; h++)
                a8[h] = fmaf(we, eW2[(h*32+hd)*256 + k], a8[h]);
        }
        int ksd = k >> 5, q2 = (k >> 3) & 3, jj = k & 7;
        #pragma unroll
        for (int h = 0; h < 8; h++)
            mfg[((ksd*64 + h + 16*q2))*8 + jj] = (_Float16)a8[h];
        #pragma unroll
        for (int n = 8; n < 16; n++)
            mfg[((ksd*64 + n + 16*q2))*8 + jj] = (_Float16)0.f;
        {
            _Float16* apj = (_Float16*)(ws + WS_APJ);
            _Float16* bpj = (_Float16*)(ws + WS_BPJ);
            int ks0 = tid >> 5, qz = (tid >> 3) & 3, ez = tid & 7;
            int ad = ((ks0*64 + 16*qz) << 3) + ez;
            #pragma unroll
            for (int bb = 0; bb < 4; bb++) {
                apj[bb*65536 + ad] = (_Float16)0.f;
                bpj[bb*65536 + ad] = (_Float16)0.f;
            }
        }
        {   // CONST parallel
            int h = tid >> 5, hd = tid & 31;
            float c = aW[64+hd]*eb2[h*32+hd] + aW[hd]*qb[h*32+hd] + aW[32+hd]*kb[h*32+hd];
            #pragma unroll
            for (int off = 16; off >= 1; off >>= 1)
                c += __shfl_xor(c, off, 32);
            if (hd == 0) ws[WS_CONST + h] = c;
        }
    }
}

// ===========================================================================
// K3: 2 i-values per block, grid (128,4) x 512 threads (R4 winner skeleton).
// Packed-f16 LN/ReLU epilogue; P stored as f16 for ctx.
// ===========================================================================
__global__ __launch_bounds__(512, 4) void k3(
    const float* __restrict__ ln_g, const float* __restrict__ ln_b,
    const float* __restrict__ ab, const float* __restrict__ ws,
    float* __restrict__ out)
{
    const int b = blockIdx.y, gx = blockIdx.x;
    const int i0 = gx*2, i1 = gx*2 + 1;
    const int tid = threadIdx.x;
    const int wave = tid >> 6, lane = tid & 63;
    const int m16 = lane & 15, quad = lane >> 4;
    const bool sp = (gx == 0);   // i0 == 0 special

    __shared__ float klds[2048];
    __shared__ float PL0[8*PLS], PL1[8*PLS];
    __shared__ __align__(16) _Float16 PH0[8*PLS], PH1[8*PLS];
    __shared__ __align__(16) _Float16 aH[2][256];
    __shared__ __align__(16) _Float16 gH[256], bH[256];
    __shared__ float2 st0[256], st1[256];
    __shared__ float stG0[256], stG1[256], stSB[256], stQB[256], stSA[256], stQA[256];
    __shared__ float baseh[16], sms[16], saqa[16];

    const half8 z8 = {(_Float16)0,(_Float16)0,(_Float16)0,(_Float16)0,
                      (_Float16)0,(_Float16)0,(_Float16)0,(_Float16)0};
    half8 ones8;
    #pragma unroll
    for (int e = 0; e < 8; e++) ones8[e] = (_Float16)1.0f;

    // ---- loads ----
    #pragma unroll
    for (int t = 0; t < 4; t++)
        klds[tid + t*512] = ws[WS_KLOG + b*2048 + tid + t*512];
    if (tid < 256) gH[tid] = (_Float16)ln_g[tid];
    else if (tid < 512) bH[tid-256] = (_Float16)ln_b[tid-256];
    {
        int hf = tid >> 8, t8 = tid & 255;
        int ih = hf ? i1 : i0;
        float av = (ih >= 1) ? ws[WS_AP + ((size_t)(b*S + ih - 1))*256 + t8] : 0.f;
        aH[hf][t8] = (_Float16)av;
        float s1 = av, s2 = av*av;
        #pragma unroll
        for (int off = 32; off >= 1; off >>= 1) {
            s1 += __shfl_xor(s1, off, 64);
            s2 += __shfl_xor(s2, off, 64);
        }
        int hw = wave >> 2, sub = wave & 3;
        if (lane == 0) { saqa[hw*8 + sub] = s1; saqa[hw*8 + 4 + sub] = s2; }
    }
    if (tid < 16) {
        int h = tid & 7, ih = (tid >> 3) ? i1 : i0;
        baseh[tid] = ws[WS_QLOG + (b*8+h)*256 + ih] + ab[0] + ws[WS_CONST + h];
    }
    __syncthreads();

    const _Float16* mfg = (const _Float16*)(ws + WS_MFG);
    const _Float16* bpj = (const _Float16*)(ws + WS_BPJ) + b*65536;
    const _Float16* apj = (const _Float16*)(ws + WS_APJ) + b*65536;
    const _Float16* vtf = (const _Float16*)(ws + WS_VTF) + b*65536;

    // ---- per-j stats via MFMA: wave handles tiles wave*2, wave*2+1 ----
    if (!sp) {
        #pragma unroll
        for (int t2 = 0; t2 < 2; t2++) {
            int tl = wave*2 + t2;
            f32x4 accGS = {}, accQB = {};
            #pragma unroll
            for (int ks = 0; ks < 8; ks++) {
                half8 bb = *(const half8*)&bpj[((tl*8+ks)*64 + lane) << 3];
                half8 ags;
                if (m16 < 2)       ags = *(const half8*)&aH[m16][ks*32 + quad*8];
                else if (m16 == 2) ags = ones8;
                else               ags = z8;
                accGS = __builtin_amdgcn_mfma_f32_16x16x32_f16(ags, bb, accGS, 0,0,0);
                accQB = __builtin_amdgcn_mfma_f32_16x16x32_f16(bb,  bb, accQB, 0,0,0);
            }
            int j = tl*16 + m16;
            if (quad == 0) { stG0[j] = accGS[0]; stG1[j] = accGS[1]; stSB[j] = accGS[2]; }
            if (quad == (m16 >> 2)) stQB[j] = accQB[m16 & 3];
        }
    } else {
        #pragma unroll
        for (int t2 = 0; t2 < 2; t2++) {
            int tl = wave*2 + t2;
            f32x4 accSB = {}, accSA = {}, accG = {}, accQA = {}, accQB = {}, accG1 = {};
            #pragma unroll
            for (int ks = 0; ks < 8; ks++) {
                int idx = ((tl*8+ks)*64 + lane) << 3;
                half8 bb = *(const half8*)&bpj[idx];
                half8 aa = *(const half8*)&apj[idx];
                half8 a1 = (m16 == 0) ? ones8 : z8;
                half8 ag1 = (m16 == 0) ? *(const half8*)&aH[1][ks*32 + quad*8] : z8;
                accSB = __builtin_amdgcn_mfma_f32_16x16x32_f16(a1, bb, accSB, 0,0,0);
                accSA = __builtin_amdgcn_mfma_f32_16x16x32_f16(a1, aa, accSA, 0,0,0);
                accG  = __builtin_amdgcn_mfma_f32_16x16x32_f16(aa, bb, accG,  0,0,0);
                accQA = __builtin_amdgcn_mfma_f32_16x16x32_f16(aa, aa, accQA, 0,0,0);
                accQB = __builtin_amdgcn_mfma_f32_16x16x32_f16(bb, bb, accQB, 0,0,0);
                accG1 = __builtin_amdgcn_mfma_f32_16x16x32_f16(ag1, bb, accG1, 0,0,0);
            }
            int j = tl*16 + m16;
            if (quad == 0) { stSB[j] = accSB[0]; stSA[j] = accSA[0]; stG1[j] = accG1[0]; }
            if (quad == (m16 >> 2)) {
                int r = m16 & 3;
                stG0[j] = accG[r]; stQA[j] = accQA[r]; stQB[j] = accQB[r];
            }
        }
    }
    __syncthreads();

    {   // per-(i,j) (inv, -mu*inv): thread = hf*256 + j
        int hf = tid >> 8, j = tid & 255;
        float2 v; v.x = 0.f; v.y = 0.f;
        if (j >= 1) {
            float sa, qa;
            if (sp && hf == 0) { sa = stSA[j]; qa = stQA[j]; }
            else {
                int base = hf ? 8 : 0;
                sa = saqa[base+0] + saqa[base+1] + saqa[base+2] + saqa[base+3];
                qa = saqa[base+4] + saqa[base+5] + saqa[base+6] + saqa[base+7];
            }
            float g = hf ? stG1[j] : stG0[j];
            float sb = stSB[j], qb2 = stQB[j];
            float mu  = (sa + sb) * (1.0f/256.0f);
            float var = (qa + qb2 + 2.f*g) * (1.0f/256.0f) - mu*mu;
            float inv = rsqrtf(var + 1e-5f);
            v.x = inv; v.y = -mu*inv;
        }
        (hf ? st1 : st0)[j] = v;
    }
    __syncthreads();

    // ---- logits MFMA, packed-f16 epilogue; tt outer ----
    f32x4 acc[2][2] = {};   // [ii][tt]
    #pragma unroll
    for (int tt = 0; tt < 2; tt++) {
        int jt = wave*2 + tt;
        float2 s0 = st0[jt*16 + m16];
        float2 s1 = st1[jt*16 + m16];
        half8 inv80 = splat8(s0.x), ty80 = splat8(s0.y);
        half8 inv81 = splat8(s1.x), ty81 = splat8(s1.y);
        #pragma unroll
        for (int ks = 0; ks < 8; ks++) {
            int k = ks*32 + quad*8;
            half8 ga  = *(const half8*)&gH[k];
            half8 be  = *(const half8*)&bH[k];
            half8 bf  = *(const half8*)&mfg[(ks*64 + lane) << 3];
            int idx2 = ((jt*8 + ks)*64 + lane) << 3;
            half8 bp = *(const half8*)&bpj[idx2];
            half8 a0 = sp ? *(const half8*)&apj[idx2] : *(const half8*)&aH[0][k];
            half8 a1 = *(const half8*)&aH[1][k];
            half8 c0 = a0 + bp;
            half8 c1 = a1 + bp;
            half8 w0 = (c0 * inv80 + ty80) * ga + be;
            half8 w1 = (c1 * inv81 + ty81) * ga + be;
            half8 af0 = __builtin_elementwise_max(w0, z8);
            half8 af1 = __builtin_elementwise_max(w1, z8);
            acc[0][tt] = __builtin_amdgcn_mfma_f32_16x16x32_f16(af0, bf, acc[0][tt], 0,0,0);
            acc[1][tt] = __builtin_amdgcn_mfma_f32_16x16x32_f16(af1, bf, acc[1][tt], 0,0,0);
        }
    }

    if (m16 < 8) {
        float basev0 = baseh[m16], basev1 = baseh[8 + m16];
        #pragma unroll
        for (int tt = 0; tt < 2; tt++)
            #pragma unroll
            for (int r = 0; r < 4; r++) {
                int jr = (wave*2 + tt)*16 + quad*4 + r;
                float kv = klds[m16*256 + jr];
                float v0 = basev0 + kv + ((jr == 0) ? -1e9f : acc[0][tt][r]);
                float v1 = basev1 + kv + ((jr == 0) ? -1e9f : acc[1][tt][r]);
                PL0[m16*PLS + jr] = v0;
                PL1[m16*PLS + jr] = v1;
            }
    }
    __syncthreads();

    // ---- softmax: wave w owns rows 2w, 2w+1 of 16 (row = i*8 + h) ----
    float* attnOut = out + 262144;
    #pragma unroll
    for (int hh = 0; hh < 2; hh++) {
        int row = wave*2 + hh;
        int ihf = row >> 3, h = row & 7;
        float* PLp = ihf ? PL1 : PL0;
        _Float16* PHp = ihf ? PH1 : PH0;
        int iv = ihf ? i1 : i0;
        float4 v = *(const float4*)&PLp[h*PLS + lane*4];
        float mv = fmaxf(fmaxf(v.x, v.y), fmaxf(v.z, v.w));
        #pragma unroll
        for (int off = 32; off >= 1; off >>= 1)
            mv = fmaxf(mv, __shfl_xor(mv, off, 64));
        float4 p;
        p.x = __expf(v.x - mv); p.y = __expf(v.y - mv);
        p.z = __expf(v.z - mv); p.w = __expf(v.w - mv);
        float ss = p.x + p.y + p.z + p.w;
        #pragma unroll
        for (int off = 32; off >= 1; off >>= 1)
            ss += __shfl_xor(ss, off, 64);
        half4 hp;
        hp[0] = (_Float16)p.x; hp[1] = (_Float16)p.y;
        hp[2] = (_Float16)p.z; hp[3] = (_Float16)p.w;
        *(half4*)&PHp[h*PLS + lane*4] = hp;
        if (lane == 0) sms[row] = ss;
        float rs = 1.0f / ss;
        float4 ao;
        ao.x = p.x*rs; ao.y = p.y*rs; ao.z = p.z*rs; ao.w = p.w*rs;
        *(float4*)&attnOut[((b*8+h)*256 + iv)*256 + lane*4] = ao;
    }
    __syncthreads();

    // ---- ctx via MFMA: wave handles col-tiles 2w, 2w+1; both i ----
    {
        f32x4 cacc[2][2] = {};   // [i][cl]
        int ct0 = wave*2;
        #pragma unroll
        for (int js = 0; js < 8; js++) {
            half8 af0, af1;
            if (m16 < 8) {
                af0 = *(const half8*)&PH0[m16*PLS + js*32 + quad*8];
                af1 = *(const half8*)&PH1[m16*PLS + js*32 + quad*8];
            } else { af0 = z8; af1 = z8; }
            #pragma unroll
            for (int cl = 0; cl < 2; cl++) {
                half8 bf = *(const half8*)&vtf[(((ct0+cl)*8 + js)*64 + lane) << 3];
                cacc[0][cl] = __builtin_amdgcn_mfma_f32_16x16x32_f16(af0, bf, cacc[0][cl], 0,0,0);
                cacc[1][cl] = __builtin_amdgcn_mfma_f32_16x16x32_f16(af1, bf, cacc[1][cl], 0,0,0);
            }
        }
        #pragma unroll
        for (int cl = 0; cl < 2; cl++) {
            int ct = ct0 + cl;
            int h = ct >> 1;
            if (quad == (h >> 2)) {
                out[(b*256 + i0)*256 + ct*16 + m16] = cacc[0][cl][h & 3] * (1.0f / sms[h]);
                out[(b*256 + i1)*256 + ct*16 + m16] = cacc[1][cl][h & 3] * (1.0f / sms[8 + h]);
            }
        }
    }
}

// ---------------------------------------------------------------------------
extern "C" void kernel_launch(void* const* d_in, const int* in_sizes, int n_in,
                              void* d_out, int out_size, void* d_ws, size_t ws_size,
                              hipStream_t stream)
{
    const float* desc = (const float*)d_in[0];
    const float* nve  = (const float*)d_in[1];
    const float* qW   = (const float*)d_in[2];
    const float* qb   = (const float*)d_in[3];
    const float* kW   = (const float*)d_in[4];
    const float* kb   = (const float*)d_in[5];
    const float* vW   = (const float*)d_in[6];
    const float* vb   = (const float*)d_in[7];
    const float* eW1  = (const float*)d_in[8];
    const float* eb1  = (const float*)d_in[9];
    const float* ln_g = (const float*)d_in[10];
    const float* ln_b = (const float*)d_in[11];
    const float* eW2  = (const float*)d_in[12];
    const float* eb2  = (const float*)d_in[13];
    const float* aW   = (const float*)d_in[14];
    const float* ab   = (const float*)d_in[15];
    float* ws  = (float*)d_ws;
    float* out = (float*)d_out;

    k1<<<dim3(209), 256, 0, stream>>>(desc, nve, qW, qb, kW, kb, vW, vb,
                                      eW1, eb1, eW2, eb2, aW, ws);
    k3<<<dim3(128, 4), 512, 0, stream>>>(ln_g, ln_b, ab, ws, out);
}

// Round 8
// 116.827 us; speedup vs baseline: 1.1110x; 1.0082x over previous
//
#include <hip/hip_runtime.h>
#include <math.h>

#define S 255
#define B 4

typedef _Float16 half8 __attribute__((ext_vector_type(8)));
typedef _Float16 half4 __attribute__((ext_vector_type(4)));
typedef float f32x4 __attribute__((ext_vector_type(4)));

// ---- workspace layout (float offsets) ----
#define WS_APJ   0          // f16[4][65536]  A' frag, row j = A'[j-1], j=0 zeroed
#define WS_BPJ   131072     // f16[4][65536]  B' frag, j-shifted
#define WS_VTF   262144     // f16[4][65536]  V^T frag: (col d, k=j)
#define WS_AP    393216     // f32[1020][256] row-major A'
#define WS_MFG   654336     // f16[4096] M in B-frag order
#define WS_CONST 656384     // f32[8]
#define WS_QLOG  656392     // f32[4][8][256]
#define WS_KLOG  664584     // f32[4][8][256]  (ends 672776)

#define PLS 272

__device__ __forceinline__ half8 cvt8(float4 a, float4 b) {
    half8 h;
    h[0]=(_Float16)a.x; h[1]=(_Float16)a.y; h[2]=(_Float16)a.z; h[3]=(_Float16)a.w;
    h[4]=(_Float16)b.x; h[5]=(_Float16)b.y; h[6]=(_Float16)b.z; h[7]=(_Float16)b.w;
    return h;
}

__device__ __forceinline__ half8 splat8(float x) {
    _Float16 hv = (_Float16)x;
    half8 v;
    #pragma unroll
    for (int e = 0; e < 8; e++) v[e] = hv;
    return v;
}

// ===========================================================================
// K1: 0..63 V->VTF | 64..127 A' | 128..191 B' | 192..207 qklog | 208 misc
// (verified body — unchanged)
// ===========================================================================
__global__ __launch_bounds__(256) void k1(
    const float* __restrict__ desc, const float* __restrict__ nve,
    const float* __restrict__ qW, const float* __restrict__ qb,
    const float* __restrict__ kW, const float* __restrict__ kb,
    const float* __restrict__ vW, const float* __restrict__ vb,
    const float* __restrict__ eW1, const float* __restrict__ eb1,
    const float* __restrict__ eW2, const float* __restrict__ eb2,
    const float* __restrict__ aW, float* __restrict__ ws)
{
    const int blk = blockIdx.x;
    const int tid = threadIdx.x;
    __shared__ _Float16 Af[4096];
    __shared__ _Float16 Bf[4096];
    const int wave = tid >> 6, lane = tid & 63;
    const int m16 = lane & 15, quad = lane >> 4;
    const int sr = tid & 63, sko = (tid >> 6) * 16;
    const half8 z8 = {(_Float16)0,(_Float16)0,(_Float16)0,(_Float16)0,
                      (_Float16)0,(_Float16)0,(_Float16)0,(_Float16)0};

    if (blk < 192) {
        const float *X, *W; int M, wst, wof, jobt, sub = blk;
        if (sub < 64)       { X=nve;  W=vW;  M=1024; wst=256; wof=0;   jobt=0; }
        else if (sub < 128) { X=desc; W=eW1; M=1020; wst=512; wof=0;   jobt=1; sub-=64; }
        else                { X=desc; W=eW1; M=1020; wst=512; wof=256; jobt=2; sub-=128; }
        int mBase = (sub>>2)*64, nBase = (sub&3)*64;
        f32x4 acc[2][2] = {};
        for (int k0 = 0; k0 < 256; k0 += 64) {
            half8 xa[2], wb[2];
            int xr = mBase + sr, wr = nBase + sr;
            #pragma unroll
            for (int hh = 0; hh < 2; hh++) {
                int kk = k0 + sko + hh*8;
                if (xr < M) xa[hh] = cvt8(*(const float4*)&X[xr*256 + kk],
                                          *(const float4*)&X[xr*256 + kk + 4]);
                else xa[hh] = z8;
                wb[hh] = cvt8(*(const float4*)&W[wr*wst + wof + kk],
                              *(const float4*)&W[wr*wst + wof + kk + 4]);
            }
            __syncthreads();
            #pragma unroll
            for (int hh = 0; hh < 2; hh++) {
                int krel = sko + hh*8;
                int c = krel >> 5, q2 = (krel >> 3) & 3;
                int ld = (sr & 15) + 16*q2, rt = sr >> 4;
                *(half8*)&Af[((rt*2 + c)*64 + ld)*8] = xa[hh];
                *(half8*)&Bf[((rt*2 + c)*64 + ld)*8] = wb[hh];
            }
            __syncthreads();
            int rt0 = (wave >> 1)*2, ct0 = (wave & 1)*2;
            #pragma unroll
            for (int c = 0; c < 2; c++) {
                half8 A0 = *(const half8*)&Af[(((rt0    )*2 + c)*64 + lane)*8];
                half8 A1 = *(const half8*)&Af[(((rt0 + 1)*2 + c)*64 + lane)*8];
                half8 B0 = *(const half8*)&Bf[(((ct0    )*2 + c)*64 + lane)*8];
                half8 B1 = *(const half8*)&Bf[(((ct0 + 1)*2 + c)*64 + lane)*8];
                acc[0][0] = __builtin_amdgcn_mfma_f32_16x16x32_f16(A0, B0, acc[0][0], 0,0,0);
                acc[0][1] = __builtin_amdgcn_mfma_f32_16x16x32_f16(A0, B1, acc[0][1], 0,0,0);
                acc[1][0] = __builtin_amdgcn_mfma_f32_16x16x32_f16(A1, B0, acc[1][0], 0,0,0);
                acc[1][1] = __builtin_amdgcn_mfma_f32_16x16x32_f16(A1, B1, acc[1][1], 0,0,0);
            }
        }
        int rt0 = (wave >> 1)*2, ct0 = (wave & 1)*2;
        if (jobt == 0) {
            _Float16* vtf = (_Float16*)(ws + WS_VTF);
            #pragma unroll
            for (int ci = 0; ci < 2; ci++) {
                int col = nBase + (ct0 + ci)*16 + m16;
                float bv = vb[col];
                int ct = col >> 4, n = col & 15;
                #pragma unroll
                for (int ri = 0; ri < 2; ri++)
                    #pragma unroll
                    for (int r = 0; r < 4; r++) {
                        int rr = mBase + (rt0 + ri)*16 + quad*4 + r;
                        int bb = rr >> 8, j = rr & 255;
                        int js = j >> 5, qv = (j >> 3) & 3, ev = j & 7;
                        float o = acc[ri][ci][r] + bv;
                        vtf[bb*65536 + (((ct*8 + js)*64 + n + 16*qv) << 3) + ev] = (_Float16)o;
                    }
            }
        } else {
            _Float16* OJ = (_Float16*)(ws + ((jobt == 1) ? WS_APJ : WS_BPJ));
            #pragma unroll
            for (int ci = 0; ci < 2; ci++) {
                int col = nBase + (ct0 + ci)*16 + m16;
                float bv = (jobt == 1) ? eb1[col] : 0.f;
                int ks = col >> 5, q = (col >> 3) & 3, e = col & 7;
                #pragma unroll
                for (int ri = 0; ri < 2; ri++)
                    #pragma unroll
                    for (int r = 0; r < 4; r++) {
                        int rr = mBase + (rt0 + ri)*16 + quad*4 + r;
                        if (rr < 1020) {
                            float o = acc[ri][ci][r] + bv;
                            int bb = rr / 255;
                            int j = rr - bb*255 + 1;
                            int jt = j >> 4, mm = j & 15;
                            OJ[bb*65536 + (((jt*8 + ks)*64 + mm + 16*q) << 3) + e] = (_Float16)o;
                            if (jobt == 1) ws[WS_AP + rr*256 + col] = o;
                        }
                    }
            }
        }
    } else if (blk < 208) {
        // qklog = nve @ fold (fold in Bf)
        {
            int d = tid;
            float f[16] = {0,0,0,0,0,0,0,0,0,0,0,0,0,0,0,0};
            for (int hd = 0; hd < 32; hd++) {
                float wq = aW[hd], wk = aW[32+hd];
                #pragma unroll
                for (int h = 0; h < 8; h++) {
                    f[h]   = fmaf(wq, qW[(h*32+hd)*256 + d], f[h]);
                    f[8+h] = fmaf(wk, kW[(h*32+hd)*256 + d], f[8+h]);
                }
            }
            int ksd = d >> 5, q2 = (d >> 3) & 3, jj = d & 7;
            #pragma unroll
            for (int n = 0; n < 16; n++)
                Bf[((ksd*64 + n + 16*q2))*8 + jj] = (_Float16)f[n];
        }
        __syncthreads();
        int mBase = (blk - 192)*64;
        f32x4 acc = {0.f,0.f,0.f,0.f};
        for (int k0 = 0; k0 < 256; k0 += 64) {
            half8 xa[2];
            #pragma unroll
            for (int hh = 0; hh < 2; hh++) {
                int kk = k0 + sko + hh*8;
                xa[hh] = cvt8(*(const float4*)&nve[(mBase + sr)*256 + kk],
                              *(const float4*)&nve[(mBase + sr)*256 + kk + 4]);
            }
            __syncthreads();
            #pragma unroll
            for (int hh = 0; hh < 2; hh++) {
                int krel = sko + hh*8;
                int c = krel >> 5, q2 = (krel >> 3) & 3;
                int ld = (sr & 15) + 16*q2, rt = sr >> 4;
                *(half8*)&Af[((rt*2 + c)*64 + ld)*8] = xa[hh];
            }
            __syncthreads();
            #pragma unroll
            for (int c = 0; c < 2; c++) {
                half8 A  = *(const half8*)&Af[((wave*2 + c)*64 + lane)*8];
                half8 Bv = *(const half8*)&Bf[(((k0 >> 5) + c)*64 + lane)*8];
                acc = __builtin_amdgcn_mfma_f32_16x16x32_f16(A, Bv, acc, 0,0,0);
            }
        }
        #pragma unroll
        for (int r = 0; r < 4; r++) {
            int rr = mBase + wave*16 + quad*4 + r;
            int bb = rr >> 8, tt2 = rr & 255;
            if (m16 < 8) ws[WS_QLOG + (bb*8 + m16)*256 + tt2] = acc[r];
            else         ws[WS_KLOG + (bb*8 + m16 - 8)*256 + tt2] = acc[r];
        }
    } else {
        // misc: MFG + CONST + zero j=0 frag rows
        _Float16* mfg = (_Float16*)(ws + WS_MFG);
        int k = tid;
        float a8[8] = {0,0,0,0,0,0,0,0};
        for (int hd = 0; hd < 32; hd++) {
            float we = aW[64+hd];
            #pragma unroll
            for (int h = 0; h < 8; h++)
                a8[h] = fmaf(we, eW2[(h*32+hd)*256 + k], a8[h]);
        }
        int ksd = k >> 5, q2 = (k >> 3) & 3, jj = k & 7;
        #pragma unroll
        for (int h = 0; h < 8; h++)
            mfg[((ksd*64 + h + 16*q2))*8 + jj] = (_Float16)a8[h];
        #pragma unroll
        for (int n = 8; n < 16; n++)
            mfg[((ksd*64 + n + 16*q2))*8 + jj] = (_Float16)0.f;
        {
            _Float16* apj = (_Float16*)(ws + WS_APJ);
            _Float16* bpj = (_Float16*)(ws + WS_BPJ);
            int ks0 = tid >> 5, qz = (tid >> 3) & 3, ez = tid & 7;
            int ad = ((ks0*64 + 16*qz) << 3) + ez;
            #pragma unroll
            for (int bb = 0; bb < 4; bb++) {
                apj[bb*65536 + ad] = (_Float16)0.f;
                bpj[bb*65536 + ad] = (_Float16)0.f;
            }
        }
        {   // CONST parallel
            int h = tid >> 5, hd = tid & 31;
            float c = aW[64+hd]*eb2[h*32+hd] + aW[hd]*qb[h*32+hd] + aW[32+hd]*kb[h*32+hd];
            #pragma unroll
            for (int off = 16; off >= 1; off >>= 1)
                c += __shfl_xor(c, off, 32);
            if (hd == 0) ws[WS_CONST + h] = c;
        }
    }
}

// ===========================================================================
// K3: 2 i-values per block, grid (128,4) x 512 threads.
// Packed-f16 LN/ReLU epilogue; P stored f16; ctx packs i0/i1 into one MFMA
// (A rows 0-7 = P_i0 heads, rows 8-15 = P_i1 heads — D rows split likewise).
// ===========================================================================
__global__ __launch_bounds__(512, 4) void k3(
    const float* __restrict__ ln_g, const float* __restrict__ ln_b,
    const float* __restrict__ ab, const float* __restrict__ ws,
    float* __restrict__ out)
{
    const int b = blockIdx.y, gx = blockIdx.x;
    const int i0 = gx*2, i1 = gx*2 + 1;
    const int tid = threadIdx.x;
    const int wave = tid >> 6, lane = tid & 63;
    const int m16 = lane & 15, quad = lane >> 4;
    const bool sp = (gx == 0);   // i0 == 0 special

    __shared__ float klds[2048];
    __shared__ float PL0[8*PLS], PL1[8*PLS];
    __shared__ __align__(16) _Float16 PH0[8*PLS], PH1[8*PLS];
    __shared__ __align__(16) _Float16 aH[2][256];
    __shared__ __align__(16) _Float16 gH[256], bH[256];
    __shared__ float2 st0[256], st1[256];
    __shared__ float stG0[256], stG1[256], stSB[256], stQB[256], stSA[256], stQA[256];
    __shared__ float baseh[16], sms[16], saqa[16];

    const half8 z8 = {(_Float16)0,(_Float16)0,(_Float16)0,(_Float16)0,
                      (_Float16)0,(_Float16)0,(_Float16)0,(_Float16)0};
    half8 ones8;
    #pragma unroll
    for (int e = 0; e < 8; e++) ones8[e] = (_Float16)1.0f;

    // ---- loads ----
    #pragma unroll
    for (int t = 0; t < 4; t++)
        klds[tid + t*512] = ws[WS_KLOG + b*2048 + tid + t*512];
    if (tid < 256) gH[tid] = (_Float16)ln_g[tid];
    else if (tid < 512) bH[tid-256] = (_Float16)ln_b[tid-256];
    {
        int hf = tid >> 8, t8 = tid & 255;
        int ih = hf ? i1 : i0;
        float av = (ih >= 1) ? ws[WS_AP + ((size_t)(b*S + ih - 1))*256 + t8] : 0.f;
        aH[hf][t8] = (_Float16)av;
        float s1 = av, s2 = av*av;
        #pragma unroll
        for (int off = 32; off >= 1; off >>= 1) {
            s1 += __shfl_xor(s1, off, 64);
            s2 += __shfl_xor(s2, off, 64);
        }
        int hw = wave >> 2, sub = wave & 3;
        if (lane == 0) { saqa[hw*8 + sub] = s1; saqa[hw*8 + 4 + sub] = s2; }
    }
    if (tid < 16) {
        int h = tid & 7, ih = (tid >> 3) ? i1 : i0;
        baseh[tid] = ws[WS_QLOG + (b*8+h)*256 + ih] + ab[0] + ws[WS_CONST + h];
    }
    __syncthreads();

    const _Float16* mfg = (const _Float16*)(ws + WS_MFG);
    const _Float16* bpj = (const _Float16*)(ws + WS_BPJ) + b*65536;
    const _Float16* apj = (const _Float16*)(ws + WS_APJ) + b*65536;
    const _Float16* vtf = (const _Float16*)(ws + WS_VTF) + b*65536;

    // ---- per-j stats via MFMA: wave handles tiles wave*2, wave*2+1 ----
    if (!sp) {
        #pragma unroll
        for (int t2 = 0; t2 < 2; t2++) {
            int tl = wave*2 + t2;
            f32x4 accGS = {}, accQB = {};
            #pragma unroll
            for (int ks = 0; ks < 8; ks++) {
                half8 bb = *(const half8*)&bpj[((tl*8+ks)*64 + lane) << 3];
                half8 ags;
                if (m16 < 2)       ags = *(const half8*)&aH[m16][ks*32 + quad*8];
                else if (m16 == 2) ags = ones8;
                else               ags = z8;
                accGS = __builtin_amdgcn_mfma_f32_16x16x32_f16(ags, bb, accGS, 0,0,0);
                accQB = __builtin_amdgcn_mfma_f32_16x16x32_f16(bb,  bb, accQB, 0,0,0);
            }
            int j = tl*16 + m16;
            if (quad == 0) { stG0[j] = accGS[0]; stG1[j] = accGS[1]; stSB[j] = accGS[2]; }
            if (quad == (m16 >> 2)) stQB[j] = accQB[m16 & 3];
        }
    } else {
        #pragma unroll
        for (int t2 = 0; t2 < 2; t2++) {
            int tl = wave*2 + t2;
            f32x4 accSB = {}, accSA = {}, accG = {}, accQA = {}, accQB = {}, accG1 = {};
            #pragma unroll
            for (int ks = 0; ks < 8; ks++) {
                int idx = ((tl*8+ks)*64 + lane) << 3;
                half8 bb = *(const half8*)&bpj[idx];
                half8 aa = *(const half8*)&apj[idx];
                half8 a1 = (m16 == 0) ? ones8 : z8;
                half8 ag1 = (m16 == 0) ? *(const half8*)&aH[1][ks*32 + quad*8] : z8;
                accSB = __builtin_amdgcn_mfma_f32_16x16x32_f16(a1, bb, accSB, 0,0,0);
                accSA = __builtin_amdgcn_mfma_f32_16x16x32_f16(a1, aa, accSA, 0,0,0);
                accG  = __builtin_amdgcn_mfma_f32_16x16x32_f16(aa, bb, accG,  0,0,0);
                accQA = __builtin_amdgcn_mfma_f32_16x16x32_f16(aa, aa, accQA, 0,0,0);
                accQB = __builtin_amdgcn_mfma_f32_16x16x32_f16(bb, bb, accQB, 0,0,0);
                accG1 = __builtin_amdgcn_mfma_f32_16x16x32_f16(ag1, bb, accG1, 0,0,0);
            }
            int j = tl*16 + m16;
            if (quad == 0) { stSB[j] = accSB[0]; stSA[j] = accSA[0]; stG1[j] = accG1[0]; }
            if (quad == (m16 >> 2)) {
                int r = m16 & 3;
                stG0[j] = accG[r]; stQA[j] = accQA[r]; stQB[j] = accQB[r];
            }
        }
    }
    __syncthreads();

    {   // per-(i,j) (inv, -mu*inv): thread = hf*256 + j
        int hf = tid >> 8, j = tid & 255;
        float2 v; v.x = 0.f; v.y = 0.f;
        if (j >= 1) {
            float sa, qa;
            if (sp && hf == 0) { sa = stSA[j]; qa = stQA[j]; }
            else {
                int base = hf ? 8 : 0;
                sa = saqa[base+0] + saqa[base+1] + saqa[base+2] + saqa[base+3];
                qa = saqa[base+4] + saqa[base+5] + saqa[base+6] + saqa[base+7];
            }
            float g = hf ? stG1[j] : stG0[j];
            float sb = stSB[j], qb2 = stQB[j];
            float mu  = (sa + sb) * (1.0f/256.0f);
            float var = (qa + qb2 + 2.f*g) * (1.0f/256.0f) - mu*mu;
            float inv = rsqrtf(var + 1e-5f);
            v.x = inv; v.y = -mu*inv;
        }
        (hf ? st1 : st0)[j] = v;
    }
    __syncthreads();

    // ---- logits MFMA, packed-f16 epilogue; tt outer ----
    f32x4 acc[2][2] = {};   // [ii][tt]
    #pragma unroll
    for (int tt = 0; tt < 2; tt++) {
        int jt = wave*2 + tt;
        float2 s0 = st0[jt*16 + m16];
        float2 s1 = st1[jt*16 + m16];
        half8 inv80 = splat8(s0.x), ty80 = splat8(s0.y);
        half8 inv81 = splat8(s1.x), ty81 = splat8(s1.y);
        #pragma unroll
        for (int ks = 0; ks < 8; ks++) {
            int k = ks*32 + quad*8;
            half8 ga  = *(const half8*)&gH[k];
            half8 be  = *(const half8*)&bH[k];
            half8 bf  = *(const half8*)&mfg[(ks*64 + lane) << 3];
            int idx2 = ((jt*8 + ks)*64 + lane) << 3;
            half8 bp = *(const half8*)&bpj[idx2];
            half8 a0 = sp ? *(const half8*)&apj[idx2] : *(const half8*)&aH[0][k];
            half8 a1 = *(const half8*)&aH[1][k];
            half8 c0 = a0 + bp;
            half8 c1 = a1 + bp;
            half8 w0 = (c0 * inv80 + ty80) * ga + be;
            half8 w1 = (c1 * inv81 + ty81) * ga + be;
            half8 af0 = __builtin_elementwise_max(w0, z8);
            half8 af1 = __builtin_elementwise_max(w1, z8);
            acc[0][tt] = __builtin_amdgcn_mfma_f32_16x16x32_f16(af0, bf, acc[0][tt], 0,0,0);
            acc[1][tt] = __builtin_amdgcn_mfma_f32_16x16x32_f16(af1, bf, acc[1][tt], 0,0,0);
        }
    }

    if (m16 < 8) {
        float basev0 = baseh[m16], basev1 = baseh[8 + m16];
        #pragma unroll
        for (int tt = 0; tt < 2; tt++)
            #pragma unroll
            for (int r = 0; r < 4; r++) {
                int jr = (wave*2 + tt)*16 + quad*4 + r;
                float kv = klds[m16*256 + jr];
                float v0 = basev0 + kv + ((jr == 0) ? -1e9f : acc[0][tt][r]);
                float v1 = basev1 + kv + ((jr == 0) ? -1e9f : acc[1][tt][r]);
                PL0[m16*PLS + jr] = v0;
                PL1[m16*PLS + jr] = v1;
            }
    }
    __syncthreads();

    // ---- softmax: wave w owns rows 2w, 2w+1 of 16 (row = i*8 + h) ----
    float* attnOut = out + 262144;
    #pragma unroll
    for (int hh = 0; hh < 2; hh++) {
        int row = wave*2 + hh;
        int ihf = row >> 3, h = row & 7;
        float* PLp = ihf ? PL1 : PL0;
        _Float16* PHp = ihf ? PH1 : PH0;
        int iv = ihf ? i1 : i0;
        float4 v = *(const float4*)&PLp[h*PLS + lane*4];
        float mv = fmaxf(fmaxf(v.x, v.y), fmaxf(v.z, v.w));
        #pragma unroll
        for (int off = 32; off >= 1; off >>= 1)
            mv = fmaxf(mv, __shfl_xor(mv, off, 64));
        float4 p;
        p.x = __expf(v.x - mv); p.y = __expf(v.y - mv);
        p.z = __expf(v.z - mv); p.w = __expf(v.w - mv);
        float ss = p.x + p.y + p.z + p.w;
        #pragma unroll
        for (int off = 32; off >= 1; off >>= 1)
            ss += __shfl_xor(ss, off, 64);
        half4 hp;
        hp[0] = (_Float16)p.x; hp[1] = (_Float16)p.y;
        hp[2] = (_Float16)p.z; hp[3] = (_Float16)p.w;
        *(half4*)&PHp[h*PLS + lane*4] = hp;
        if (lane == 0) sms[row] = ss;
        float rs = 1.0f / ss;
        float4 ao;
        ao.x = p.x*rs; ao.y = p.y*rs; ao.z = p.z*rs; ao.w = p.w*rs;
        *(float4*)&attnOut[((b*8+h)*256 + iv)*256 + lane*4] = ao;
    }
    __syncthreads();

    // ---- ctx via MFMA: i0 in A-rows 0-7, i1 in A-rows 8-15; one MFMA per tile ----
    {
        f32x4 cacc[2] = {};   // [cl]
        int ct0 = wave*2;
        #pragma unroll
        for (int js = 0; js < 8; js++) {
            half8 af;
            if (m16 < 8) af = *(const half8*)&PH0[m16*PLS + js*32 + quad*8];
            else         af = *(const half8*)&PH1[(m16 - 8)*PLS + js*32 + quad*8];
            #pragma unroll
            for (int cl = 0; cl < 2; cl++) {
                half8 bf = *(const half8*)&vtf[(((ct0+cl)*8 + js)*64 + lane) << 3];
                cacc[cl] = __builtin_amdgcn_mfma_f32_16x16x32_f16(af, bf, cacc[cl], 0,0,0);
            }
        }
        #pragma unroll
        for (int cl = 0; cl < 2; cl++) {
            int ct = ct0 + cl;
            int h = ct >> 1;
            // D row = quad*4 + r; i0 head h at row h, i1 head h at row 8+h
            if (quad == (h >> 2))
                out[(b*256 + i0)*256 + ct*16 + m16] = cacc[cl][h & 3] * (1.0f / sms[h]);
            if (quad == 2 + (h >> 2))
                out[(b*256 + i1)*256 + ct*16 + m16] = cacc[cl][h & 3] * (1.0f / sms[8 + h]);
        }
    }
}

// ---------------------------------------------------------------------------
extern "C" void kernel_launch(void* const* d_in, const int* in_sizes, int n_in,
                              void* d_out, int out_size, void* d_ws, size_t ws_size,
                              hipStream_t stream)
{
    const float* desc = (const float*)d_in[0];
    const float* nve  = (const float*)d_in[1];
    const float* qW   = (const float*)d_in[2];
    const float* qb   = (const float*)d_in[3];
    const float* kW   = (const float*)d_in[4];
    const float* kb   = (const float*)d_in[5];
    const float* vW   = (const float*)d_in[6];
    const float* vb   = (const float*)d_in[7];
    const float* eW1  = (const float*)d_in[8];
    const float* eb1  = (const float*)d_in[9];
    const float* ln_g = (const float*)d_in[10];
    const float* ln_b = (const float*)d_in[11];
    const float* eW2  = (const float*)d_in[12];
    const float* eb2  = (const float*)d_in[13];
    const float* aW   = (const float*)d_in[14];
    const float* ab   = (const float*)d_in[15];
    float* ws  = (float*)d_ws;
    float* out = (float*)d_out;

    k1<<<dim3(209), 256, 0, stream>>>(desc, nve, qW, qb, kW, kb, vW, vb,
                                      eW1, eb1, eW2, eb2, aW, ws);
    k3<<<dim3(128, 4), 512, 0, stream>>>(ln_g, ln_b, ab, ws, out);
}